// Round 1
// baseline (166.287 us; speedup 1.0000x reference)
//
#include <hip/hip_runtime.h>
#include <math.h>

// ---------------- workspace layout (float offsets) ----------------
#define NHEAD     10004
#define OFF_HEAD  0        // 10004 head logits
#define OFF_H0    10004    // 512  projected vec, cluster 0 (h0..h3 contiguous)
#define OFF_C0    10964    // 10000 cluster-0 logits
#define OFF_C1    20964    // 20000
#define OFF_C2    40964    // 40000
#define OFF_C3    80964    // 20000
#define OFF_P     100964   // per-unit exp partials (NUNITS floats)

// ---- uniform 16KB work units: head 4 rows | c0 8 | c1 16 | c2 32 | c3 64 ----
#define U_HEAD 2501        // 2501*4  = 10004 exact
#define B_C0   2501        // c0 units [2501,3751): 1250*8  = 10000 exact
#define B_C1   3751        // c1 units [3751,5001): 1250*16 = 20000 exact
#define B_C2   5001        // c2 units [5001,6251): 1250*32 = 40000 exact
#define B_C3   6251        // c3 units [6251,6564): 313*64  = 20032 (last clamped)
#define NUNITS 6564
#define NWAVES 3284        // 821 blocks * 4 waves; each wave: u=wid, wid+NWAVES

__device__ __forceinline__ float wave_sum(float v) {
  v += __shfl_xor(v, 32, 64);
  v += __shfl_xor(v, 16, 64);
  v += __shfl_xor(v, 8, 64);
  v += __shfl_xor(v, 4, 64);
  v += __shfl_xor(v, 2, 64);
  v += __shfl_xor(v, 1, 64);
  return v;
}

__device__ __forceinline__ float dot4(float4 a, float4 c) {
  return a.x * c.x + a.y * c.y + a.z * c.z + a.w * c.w;
}

// Kernel A: 960 projection rows, 1 row/wave, loads batched for MLP.
__global__ __launch_bounds__(256) void proj_kernel(
    const float* __restrict__ feat,
    const float* __restrict__ p0, const float* __restrict__ p1,
    const float* __restrict__ p2, const float* __restrict__ p3,
    float* __restrict__ ws) {
  __shared__ __align__(16) float sf[1024];
  ((float4*)sf)[threadIdx.x] = ((const float4*)feat)[threadIdx.x];
  __syncthreads();
  const float4* sf4 = (const float4*)sf;
  const int lane = threadIdx.x & 63;
  const int pr = blockIdx.x * 4 + (threadIdx.x >> 6);  // 0..959
  const float* src;
  if (pr < 512)      src = p0 + (size_t)pr * 1024;
  else if (pr < 768) src = p1 + (size_t)(pr - 512) * 1024;
  else if (pr < 896) src = p2 + (size_t)(pr - 768) * 1024;
  else               src = p3 + (size_t)(pr - 896) * 1024;
  const float4* src4 = (const float4*)src;
  float4 ld[4];
#pragma unroll
  for (int j = 0; j < 4; ++j) ld[j] = src4[lane + j * 64];
  float acc = 0.f;
#pragma unroll
  for (int j = 0; j < 4; ++j) acc += dot4(ld[j], sf4[lane + j * 64]);
  acc = wave_sum(acc);
  if (lane == 0) ws[NHEAD + pr] = acc;
}

// One uniform 16KB unit. All 16 float4 global loads issued before any reduce.
__device__ __forceinline__ void process_unit(
    int u, int lane, const float* sh,
    const float* __restrict__ head_w, const float* __restrict__ w0,
    const float* __restrict__ w1, const float* __restrict__ w2,
    const float* __restrict__ w3, float* __restrict__ ws) {
  float esum = 0.f;
  if (u < B_C0) {                     // head: 4 rows, D=1024
    const float4* sf4 = (const float4*)sh;
    const int r0 = u * 4;
    float4 ld[16];
#pragma unroll
    for (int k = 0; k < 4; ++k) {
      const float4* w4 = (const float4*)head_w + (size_t)(r0 + k) * 256;
#pragma unroll
      for (int j = 0; j < 4; ++j) ld[k * 4 + j] = w4[lane + j * 64];
    }
    float acc[4];
#pragma unroll
    for (int k = 0; k < 4; ++k) {
      float a = 0.f;
#pragma unroll
      for (int j = 0; j < 4; ++j) a += dot4(ld[k * 4 + j], sf4[lane + j * 64]);
      acc[k] = a;
    }
#pragma unroll
    for (int k = 0; k < 4; ++k) {
      float a = wave_sum(acc[k]);
      if (lane == 0) { ws[OFF_HEAD + r0 + k] = a; esum += expf(a); }
    }
  } else if (u < B_C1) {              // c0: 8 rows, h=512
    const float4* h4 = (const float4*)(sh + 1024);
    const float4 cv0 = h4[lane], cv1 = h4[lane + 64];
    const int r0 = (u - B_C0) * 8;
    float4 ld[16];
#pragma unroll
    for (int k = 0; k < 8; ++k) {
      const float4* w4 = (const float4*)w0 + (size_t)(r0 + k) * 128;
      ld[k * 2] = w4[lane]; ld[k * 2 + 1] = w4[lane + 64];
    }
    float acc[8];
#pragma unroll
    for (int k = 0; k < 8; ++k)
      acc[k] = dot4(ld[k * 2], cv0) + dot4(ld[k * 2 + 1], cv1);
#pragma unroll
    for (int k = 0; k < 8; ++k) {
      float a = wave_sum(acc[k]);
      if (lane == 0) { ws[OFF_C0 + r0 + k] = a; esum += expf(a); }
    }
  } else if (u < B_C2) {              // c1: 16 rows, h=256
    const float4 cv = ((const float4*)(sh + 1536))[lane];
    const int r0 = (u - B_C1) * 16;
    float4 ld[16];
#pragma unroll
    for (int k = 0; k < 16; ++k)
      ld[k] = ((const float4*)w1)[(size_t)(r0 + k) * 64 + lane];
    float acc[16];
#pragma unroll
    for (int k = 0; k < 16; ++k) acc[k] = dot4(ld[k], cv);
#pragma unroll
    for (int k = 0; k < 16; ++k) {
      float a = wave_sum(acc[k]);
      if (lane == 0) { ws[OFF_C1 + r0 + k] = a; esum += expf(a); }
    }
  } else if (u < B_C3) {              // c2: 32 rows, h=128, 2 rows per wave-load
    const float4 cv = ((const float4*)(sh + 1792))[lane & 31];
    const int r0 = (u - B_C2) * 32;
    float4 ld[16];
#pragma unroll
    for (int p = 0; p < 16; ++p)
      ld[p] = ((const float4*)w2)[(size_t)(r0 + 2 * p) * 32 + lane];
#pragma unroll
    for (int p = 0; p < 16; ++p) {
      float a = dot4(ld[p], cv);
      a += __shfl_xor(a, 1, 64);
      a += __shfl_xor(a, 2, 64);
      a += __shfl_xor(a, 4, 64);
      a += __shfl_xor(a, 8, 64);
      a += __shfl_xor(a, 16, 64);
      if ((lane & 31) == 0) {
        int r = r0 + 2 * p + (lane >> 5);
        ws[OFF_C2 + r] = a; esum += expf(a);
      }
    }
  } else {                            // c3: 64 rows, h=64, 4 rows per wave-load
    const float4 cv = ((const float4*)(sh + 1920))[lane & 15];
    const int r0 = (u - B_C3) * 64;
    float4 ld[16];
#pragma unroll
    for (int p = 0; p < 16; ++p) {
      int rb = r0 + 4 * p;
      int rbc = min(rb, 19996);
      ld[p] = ((const float4*)w3)[(size_t)rbc * 16 + lane];
    }
#pragma unroll
    for (int p = 0; p < 16; ++p) {
      int rb = r0 + 4 * p;
      float a = dot4(ld[p], cv);
      a += __shfl_xor(a, 1, 64);
      a += __shfl_xor(a, 2, 64);
      a += __shfl_xor(a, 4, 64);
      a += __shfl_xor(a, 8, 64);
      if ((lane & 15) == 0 && rb < 20000) {
        int r = rb + (lane >> 4);
        ws[OFF_C3 + r] = a; esum += expf(a);
      }
    }
  }
  esum = wave_sum(esum);
  if (lane == 0) ws[OFF_P + u] = esum;
}

// Kernel B: 821 blocks, 3284 waves, 2 uniform 16KB units per wave.
__global__ __launch_bounds__(256) void main_kernel(
    const float* __restrict__ feat, const float* __restrict__ head_w,
    const float* __restrict__ w0, const float* __restrict__ w1,
    const float* __restrict__ w2, const float* __restrict__ w3,
    float* __restrict__ ws) {
  __shared__ __align__(16) float sh[1984];  // feat[1024] | h0[512] h1[256] h2[128] h3[64]
  const int t = threadIdx.x;
  ((float4*)sh)[t] = ((const float4*)feat)[t];
  if (t < 240) ((float4*)(sh + 1024))[t] = ((const float4*)(ws + OFF_H0))[t];
  __syncthreads();
  const int lane = t & 63;
  const int wid = blockIdx.x * 4 + (t >> 6);
#pragma unroll 1
  for (int u = wid; u < NUNITS; u += NWAVES)
    process_unit(u, lane, sh, head_w, w0, w1, w2, w3, ws);
}

// Kernel C: single 1024-thread block. Target gathers issued branchlessly at
// entry (addr = t + (t>=10000)*964 by layout design), overlapping the
// per-unit partial reduction; then 5 LSEs and the mean.
__global__ __launch_bounds__(1024) void finalize_kernel(
    const int* __restrict__ targets, float* __restrict__ ws,
    float* __restrict__ out) {
  const int tid = threadIdx.x;
  const int wv = tid >> 6, lane = tid & 63;
  // 1) issue all 4 gathers early — no dependence on the LSE reduction
  float tv[4]; int sg[4];
#pragma unroll
  for (int it = 0; it < 4; ++it) {
    int tgt = targets[tid + it * 1024];
    int addr = tgt + ((tgt >= 10000) ? 964 : 0);
    tv[it] = ws[addr];
    sg[it] = (tgt >= 10000) + (tgt >= 20000) + (tgt >= 40000) + (tgt >= 80000);
  }
  // 2) segmented reduction of 6564 per-unit partials
  float a0 = 0.f, a1 = 0.f, a2 = 0.f, a3 = 0.f, a4 = 0.f;
#pragma unroll
  for (int it = 0; it < 7; ++it) {
    int i = tid + it * 1024;
    if (i < NUNITS) {
      float v = ws[OFF_P + i];
      if (i < B_C0)      a0 += v;
      else if (i < B_C1) a1 += v;
      else if (i < B_C2) a2 += v;
      else if (i < B_C3) a3 += v;
      else               a4 += v;
    }
  }
  a0 = wave_sum(a0); a1 = wave_sum(a1); a2 = wave_sum(a2);
  a3 = wave_sum(a3); a4 = wave_sum(a4);
  __shared__ float r5[16][5];
  __shared__ float slse[5];
  if (lane == 0) { r5[wv][0] = a0; r5[wv][1] = a1; r5[wv][2] = a2; r5[wv][3] = a3; r5[wv][4] = a4; }
  __syncthreads();
  if (tid < 5) {
    float s = 0.f;
#pragma unroll
    for (int w = 0; w < 16; ++w) s += r5[w][tid];
    slse[tid] = logf(s);
  }
  __syncthreads();
  const float lse0 = slse[0], lse1 = slse[1], lse2 = slse[2], lse3 = slse[3], lse4 = slse[4];
  const float g0 = ws[10000] - lse0, g1 = ws[10001] - lse0;
  const float g2 = ws[10002] - lse0, g3 = ws[10003] - lse0;
  float s = 0.f;
#pragma unroll
  for (int it = 0; it < 4; ++it) {
    int e = sg[it];
    float lseS = (e == 0) ? lse0 : (e == 1) ? lse1 : (e == 2) ? lse2 : (e == 3) ? lse3 : lse4;
    float gS   = (e == 0) ? 0.f  : (e == 1) ? g0   : (e == 2) ? g1   : (e == 3) ? g2   : g3;
    s += tv[it] - lseS + gS;
  }
  s = wave_sum(s);
  if (lane == 0) r5[wv][0] = s;
  __syncthreads();
  if (tid == 0) {
    float tot = 0.f;
#pragma unroll
    for (int w = 0; w < 16; ++w) tot += r5[w][0];
    out[0] = -tot * (1.f / 4096.f);
  }
}

extern "C" void kernel_launch(void* const* d_in, const int* in_sizes, int n_in,
                              void* d_out, int out_size, void* d_ws, size_t ws_size,
                              hipStream_t stream) {
  const float* feat    = (const float*)d_in[0];
  const int*   targets = (const int*)d_in[1];
  const float* head_w  = (const float*)d_in[2];
  const float* t0p = (const float*)d_in[3];
  const float* t0w = (const float*)d_in[4];
  const float* t1p = (const float*)d_in[5];
  const float* t1w = (const float*)d_in[6];
  const float* t2p = (const float*)d_in[7];
  const float* t2w = (const float*)d_in[8];
  const float* t3p = (const float*)d_in[9];
  const float* t3w = (const float*)d_in[10];
  float* ws  = (float*)d_ws;
  float* out = (float*)d_out;

  proj_kernel<<<240, 256, 0, stream>>>(feat, t0p, t1p, t2p, t3p, ws);
  main_kernel<<<821, 256, 0, stream>>>(feat, head_w, t0w, t1w, t2w, t3w, ws);
  finalize_kernel<<<1, 1024, 0, stream>>>(targets, ws, out);
}

// Round 2
// 158.460 us; speedup vs baseline: 1.0494x; 1.0494x over previous
//
#include <hip/hip_runtime.h>
#include <math.h>

// ---------------- workspace layout (float offsets) ----------------
#define NHEAD     10004
#define OFF_HEAD  0        // 10004 head logits
#define OFF_H0    10004    // 512  projected vec, cluster 0 (h0..h3 contiguous)
#define OFF_C0    10964    // 10000 cluster-0 logits
#define OFF_C1    20964    // 20000
#define OFF_C2    40964    // 40000
#define OFF_C3    80964    // 20000
#define OFF_P     100964   // per-unit exp partials (NUNITS floats)

// ---- uniform 8KB units: head 2 rows | c0 4 | c1 8 | c2 16 | c3 32 ----
// ALL exact divisions — no clamps anywhere.
#define B_C0   5002        // head units [0,5002):     5002*2  = 10004
#define B_C1   7502        // c0 units [5002,7502):    2500*4  = 10000
#define B_C2   10002       // c1 units [7502,10002):   2500*8  = 20000
#define B_C3   12502       // c2 units [10002,12502):  2500*16 = 40000
#define NUNITS 13127       // c3 units [12502,13127):  625*32  = 20000

__device__ __forceinline__ float wave_sum(float v) {
  v += __shfl_xor(v, 32, 64);
  v += __shfl_xor(v, 16, 64);
  v += __shfl_xor(v, 8, 64);
  v += __shfl_xor(v, 4, 64);
  v += __shfl_xor(v, 2, 64);
  v += __shfl_xor(v, 1, 64);
  return v;
}

__device__ __forceinline__ float dot4(float4 a, float4 c) {
  return a.x * c.x + a.y * c.y + a.z * c.z + a.w * c.w;
}

// Kernel A: 960 projection rows, 1 row/wave, loads batched.
__global__ __launch_bounds__(256) void proj_kernel(
    const float* __restrict__ feat,
    const float* __restrict__ p0, const float* __restrict__ p1,
    const float* __restrict__ p2, const float* __restrict__ p3,
    float* __restrict__ ws) {
  __shared__ __align__(16) float sf[1024];
  ((float4*)sf)[threadIdx.x] = ((const float4*)feat)[threadIdx.x];
  __syncthreads();
  const float4* sf4 = (const float4*)sf;
  const int lane = threadIdx.x & 63;
  const int pr = blockIdx.x * 4 + (threadIdx.x >> 6);  // 0..959
  const float* src;
  if (pr < 512)      src = p0 + (size_t)pr * 1024;
  else if (pr < 768) src = p1 + (size_t)(pr - 512) * 1024;
  else if (pr < 896) src = p2 + (size_t)(pr - 768) * 1024;
  else               src = p3 + (size_t)(pr - 896) * 1024;
  const float4* src4 = (const float4*)src;
  float4 ld[4];
#pragma unroll
  for (int j = 0; j < 4; ++j) ld[j] = src4[lane + j * 64];
  float acc = 0.f;
#pragma unroll
  for (int j = 0; j < 4; ++j) acc += dot4(ld[j], sf4[lane + j * 64]);
  acc = wave_sum(acc);
  if (lane == 0) ws[NHEAD + pr] = acc;
}

// One uniform 8KB unit: 8 float4 loads per lane, issued before any reduce.
// Butterfly leaves row-sums in ALL lanes -> esum accumulated unmasked, no
// final esum reduction (c2/c3 need 1-2 cross-group shuffles only).
__device__ __forceinline__ void process_unit(
    int u, int lane, const float* sh,
    const float* __restrict__ head_w, const float* __restrict__ w0,
    const float* __restrict__ w1, const float* __restrict__ w2,
    const float* __restrict__ w3, float* __restrict__ ws) {
  float esum = 0.f;
  if (u < B_C0) {                     // head: 2 rows, D=1024
    const float4* sf4 = (const float4*)sh;
    const int r0 = u * 2;
    const float4* w4 = (const float4*)head_w + (size_t)r0 * 256;
    float4 ld[8];
#pragma unroll
    for (int j = 0; j < 4; ++j) ld[j] = w4[lane + j * 64];
#pragma unroll
    for (int j = 0; j < 4; ++j) ld[4 + j] = w4[256 + lane + j * 64];
    float a0 = 0.f, a1 = 0.f;
#pragma unroll
    for (int j = 0; j < 4; ++j) {
      a0 += dot4(ld[j], sf4[lane + j * 64]);
      a1 += dot4(ld[4 + j], sf4[lane + j * 64]);
    }
    a0 = wave_sum(a0); a1 = wave_sum(a1);
    if (lane == 0) { ws[OFF_HEAD + r0] = a0; ws[OFF_HEAD + r0 + 1] = a1; }
    esum = expf(a0) + expf(a1);
  } else if (u < B_C1) {              // c0: 4 rows, h=512
    const float4* h4 = (const float4*)(sh + 1024);
    const float4 cv0 = h4[lane], cv1 = h4[lane + 64];
    const int r0 = (u - B_C0) * 4;
    const float4* w4 = (const float4*)w0 + (size_t)r0 * 128;
    float4 ld[8];
#pragma unroll
    for (int k = 0; k < 4; ++k) {
      ld[2 * k]     = w4[k * 128 + lane];
      ld[2 * k + 1] = w4[k * 128 + lane + 64];
    }
    float acc[4];
#pragma unroll
    for (int k = 0; k < 4; ++k)
      acc[k] = dot4(ld[2 * k], cv0) + dot4(ld[2 * k + 1], cv1);
#pragma unroll
    for (int k = 0; k < 4; ++k) {
      float a = wave_sum(acc[k]);
      if (lane == 0) ws[OFF_C0 + r0 + k] = a;
      esum += expf(a);
    }
  } else if (u < B_C2) {              // c1: 8 rows, h=256
    const float4 cv = ((const float4*)(sh + 1536))[lane];
    const int r0 = (u - B_C1) * 8;
    float4 ld[8];
#pragma unroll
    for (int k = 0; k < 8; ++k)
      ld[k] = ((const float4*)w1)[(size_t)(r0 + k) * 64 + lane];
    float acc[8];
#pragma unroll
    for (int k = 0; k < 8; ++k) acc[k] = dot4(ld[k], cv);
#pragma unroll
    for (int k = 0; k < 8; ++k) {
      float a = wave_sum(acc[k]);
      if (lane == 0) ws[OFF_C1 + r0 + k] = a;
      esum += expf(a);
    }
  } else if (u < B_C3) {              // c2: 16 rows, h=128, 2 rows/wave-load
    const float4 cv = ((const float4*)(sh + 1792))[lane & 31];
    const int r0 = (u - B_C2) * 16;
    float4 ld[8];
#pragma unroll
    for (int p = 0; p < 8; ++p)
      ld[p] = ((const float4*)w2)[(size_t)(r0 + 2 * p) * 32 + lane];
#pragma unroll
    for (int p = 0; p < 8; ++p) {
      float a = dot4(ld[p], cv);
      a += __shfl_xor(a, 1, 64);
      a += __shfl_xor(a, 2, 64);
      a += __shfl_xor(a, 4, 64);
      a += __shfl_xor(a, 8, 64);
      a += __shfl_xor(a, 16, 64);     // each 32-half holds its row sum
      if ((lane & 31) == 0) ws[OFF_C2 + r0 + 2 * p + (lane >> 5)] = a;
      esum += expf(a);                // per-lane: its half's 8 rows
    }
    esum += __shfl_xor(esum, 32, 64); // combine the two halves
  } else {                            // c3: 32 rows, h=64, 4 rows/wave-load
    const float4 cv = ((const float4*)(sh + 1920))[lane & 15];
    const int r0 = (u - B_C3) * 32;
    float4 ld[8];
#pragma unroll
    for (int p = 0; p < 8; ++p)
      ld[p] = ((const float4*)w3)[(size_t)(r0 + 4 * p) * 16 + lane];
#pragma unroll
    for (int p = 0; p < 8; ++p) {
      float a = dot4(ld[p], cv);
      a += __shfl_xor(a, 1, 64);
      a += __shfl_xor(a, 2, 64);
      a += __shfl_xor(a, 4, 64);
      a += __shfl_xor(a, 8, 64);      // each 16-group holds its row sum
      if ((lane & 15) == 0) ws[OFF_C3 + r0 + 4 * p + (lane >> 4)] = a;
      esum += expf(a);                // per-lane: its quarter's 8 rows
    }
    esum += __shfl_xor(esum, 16, 64);
    esum += __shfl_xor(esum, 32, 64); // combine the four quarters
  }
  if (lane == 0) ws[OFF_P + u] = esum;
}

// Kernel B: 3282 blocks, 13128 waves, exactly 1 uniform 8KB unit per wave.
// __launch_bounds__(256,4): cap VGPR at 128 so the ld[8] batch + 8
// independent shuffle chains actually stay in registers (r1 got squeezed
// to 60 VGPRs and the compiler serialized everything).
__global__ __launch_bounds__(256, 4) void main_kernel(
    const float* __restrict__ feat, const float* __restrict__ head_w,
    const float* __restrict__ w0, const float* __restrict__ w1,
    const float* __restrict__ w2, const float* __restrict__ w3,
    float* __restrict__ ws) {
  __shared__ __align__(16) float sh[1984];  // feat[1024] | h0[512] h1[256] h2[128] h3[64]
  const int t = threadIdx.x;
  ((float4*)sh)[t] = ((const float4*)feat)[t];
  if (t < 240) ((float4*)(sh + 1024))[t] = ((const float4*)(ws + OFF_H0))[t];
  __syncthreads();
  const int lane = t & 63;
  const int u = blockIdx.x * 4 + (t >> 6);
  if (u < NUNITS)
    process_unit(u, lane, sh, head_w, w0, w1, w2, w3, ws);
}

// Kernel C: single 1024-thread block. Target gathers issued branchlessly at
// entry (addr = t + (t>=10000)*964 by layout design), overlapping the
// per-unit partial reduction; then 5 LSEs and the mean.
__global__ __launch_bounds__(1024) void finalize_kernel(
    const int* __restrict__ targets, float* __restrict__ ws,
    float* __restrict__ out) {
  const int tid = threadIdx.x;
  const int wv = tid >> 6, lane = tid & 63;
  // 1) issue all 4 gathers early — no dependence on the LSE reduction
  float tv[4]; int sg[4];
#pragma unroll
  for (int it = 0; it < 4; ++it) {
    int tgt = targets[tid + it * 1024];
    int addr = tgt + ((tgt >= 10000) ? 964 : 0);
    tv[it] = ws[addr];
    sg[it] = (tgt >= 10000) + (tgt >= 20000) + (tgt >= 40000) + (tgt >= 80000);
  }
  // 2) segmented reduction of 13127 per-unit partials
  float a0 = 0.f, a1 = 0.f, a2 = 0.f, a3 = 0.f, a4 = 0.f;
#pragma unroll
  for (int it = 0; it < 13; ++it) {
    int i = tid + it * 1024;
    if (i < NUNITS) {
      float v = ws[OFF_P + i];
      if (i < B_C0)      a0 += v;
      else if (i < B_C1) a1 += v;
      else if (i < B_C2) a2 += v;
      else if (i < B_C3) a3 += v;
      else               a4 += v;
    }
  }
  a0 = wave_sum(a0); a1 = wave_sum(a1); a2 = wave_sum(a2);
  a3 = wave_sum(a3); a4 = wave_sum(a4);
  __shared__ float r5[16][5];
  __shared__ float slse[5];
  if (lane == 0) { r5[wv][0] = a0; r5[wv][1] = a1; r5[wv][2] = a2; r5[wv][3] = a3; r5[wv][4] = a4; }
  __syncthreads();
  if (tid < 5) {
    float s = 0.f;
#pragma unroll
    for (int w = 0; w < 16; ++w) s += r5[w][tid];
    slse[tid] = logf(s);
  }
  __syncthreads();
  const float lse0 = slse[0], lse1 = slse[1], lse2 = slse[2], lse3 = slse[3], lse4 = slse[4];
  const float g0 = ws[10000] - lse0, g1 = ws[10001] - lse0;
  const float g2 = ws[10002] - lse0, g3 = ws[10003] - lse0;
  float s = 0.f;
#pragma unroll
  for (int it = 0; it < 4; ++it) {
    int e = sg[it];
    float lseS = (e == 0) ? lse0 : (e == 1) ? lse1 : (e == 2) ? lse2 : (e == 3) ? lse3 : lse4;
    float gS   = (e == 0) ? 0.f  : (e == 1) ? g0   : (e == 2) ? g1   : (e == 3) ? g2   : g3;
    s += tv[it] - lseS + gS;
  }
  s = wave_sum(s);
  if (lane == 0) r5[wv][0] = s;
  __syncthreads();
  if (tid == 0) {
    float tot = 0.f;
#pragma unroll
    for (int w = 0; w < 16; ++w) tot += r5[w][0];
    out[0] = -tot * (1.f / 4096.f);
  }
}

extern "C" void kernel_launch(void* const* d_in, const int* in_sizes, int n_in,
                              void* d_out, int out_size, void* d_ws, size_t ws_size,
                              hipStream_t stream) {
  const float* feat    = (const float*)d_in[0];
  const int*   targets = (const int*)d_in[1];
  const float* head_w  = (const float*)d_in[2];
  const float* t0p = (const float*)d_in[3];
  const float* t0w = (const float*)d_in[4];
  const float* t1p = (const float*)d_in[5];
  const float* t1w = (const float*)d_in[6];
  const float* t2p = (const float*)d_in[7];
  const float* t2w = (const float*)d_in[8];
  const float* t3p = (const float*)d_in[9];
  const float* t3w = (const float*)d_in[10];
  float* ws  = (float*)d_ws;
  float* out = (float*)d_out;

  proj_kernel<<<240, 256, 0, stream>>>(feat, t0p, t1p, t2p, t3p, ws);
  main_kernel<<<3282, 256, 0, stream>>>(feat, head_w, t0w, t1w, t2w, t3w, ws);
  finalize_kernel<<<1, 1024, 0, stream>>>(targets, ws, out);
}